// Round 10
// baseline (7168.578 us; speedup 1.0000x reference)
//
#include <hip/hip_runtime.h>
#include <cstdint>
#include <cstddef>

// Problem dims (fixed): B=64, T=512, D=1024, U=1024
#define NB 64
#define NT 512
#define ND 1024
#define NU 1024

typedef short s16x8 __attribute__((ext_vector_type(8)));   // 8 bf16 (bit pattern)
typedef float f32x4 __attribute__((ext_vector_type(4)));
typedef unsigned int u32x2 __attribute__((ext_vector_type(2)));
typedef unsigned int u32x4 __attribute__((ext_vector_type(4)));
typedef unsigned short u16;

__device__ __forceinline__ u16 f2bf(float f) {
  unsigned int u = __float_as_uint(f);
  u += 0x7fffu + ((u >> 16) & 1u);           // round-to-nearest-even
  return (u16)(u >> 16);
}
__device__ __forceinline__ float bf2f(u16 s) {
  return __uint_as_float(((unsigned int)s) << 16);
}
__device__ __forceinline__ float hsig(float x) {
  return fminf(fmaxf(0.2f * x + 0.5f, 0.0f), 1.0f);
}
__device__ __forceinline__ float ftanh(float x) {
  float e = __expf(2.0f * x);
  return 1.0f - 2.0f / (e + 1.0f);
}
__device__ __forceinline__ f32x4 mfma16(s16x8 a, s16x8 b, f32x4 c) {
  return __builtin_amdgcn_mfma_f32_16x16x32_bf16(a, b, c, 0, 0, 0);
}

// no-return far atomic swaps: execute at the device coherent point; vmcnt ack
// == globally visible (proven R4/R5). Publish primitive for all cross-block data.
__device__ __forceinline__ void atomic_swap_u32(unsigned int* p, unsigned int v) {
  asm volatile("global_atomic_swap %0, %1, off" :: "v"(p), "v"(v) : "memory");
}
__device__ __forceinline__ void atomic_swap_u64(unsigned int* p, u32x2 v) {
  asm volatile("global_atomic_swap_x2 %0, %1, off" :: "v"(p), "v"(v) : "memory");
}

// consumer A-fragment load: STAGED -> plain cached (t-indexed slots make stale
// lines benign); fallback -> L3 bypass
template <int STAGED>
__device__ __forceinline__ void ldx4(s16x8& d, const u16* a) {
  if constexpr (STAGED)
    asm volatile("global_load_dwordx4 %0, %1, off" : "=v"(d) : "v"(a));
  else
    asm volatile("global_load_dwordx4 %0, %1, off sc0 sc1" : "=v"(d) : "v"(a));
}

#define WAIT_VM0() do { \
    asm volatile("s_waitcnt vmcnt(0)" ::: "memory"); \
    __builtin_amdgcn_sched_barrier(0); \
  } while (0)
#define WAIT_VM(N) do { \
    asm volatile("s_waitcnt vmcnt(" #N ")" ::: "memory"); \
    __builtin_amdgcn_sched_barrier(0); \
  } while (0)

// ---------------------------------------------------------------------------
// Kernel 0: W (1024x4096 f32) -> Wt (4096x1024 bf16), LDS-tiled transpose.
// ---------------------------------------------------------------------------
__global__ __launch_bounds__(256) void wt_cvt(const float* __restrict__ W,
                                              u16* __restrict__ Wt) {
  __shared__ u16 T[64][65];
  const int tid = threadIdx.x;
  const int k0 = (blockIdx.x & 15) * 64;
  const int n0 = (blockIdx.x >> 4) * 64;
  const int r = tid >> 2, c4 = (tid & 3) * 16;
  {
    const float* src = W + (size_t)(k0 + r) * 4096 + n0 + c4;
#pragma unroll
    for (int j = 0; j < 4; ++j) {
      float4 v = ((const float4*)src)[j];
      T[r][c4 + j * 4 + 0] = f2bf(v.x); T[r][c4 + j * 4 + 1] = f2bf(v.y);
      T[r][c4 + j * 4 + 2] = f2bf(v.z); T[r][c4 + j * 4 + 3] = f2bf(v.w);
    }
  }
  __syncthreads();
  {
    u16 tmp[16];
#pragma unroll
    for (int i = 0; i < 16; ++i) tmp[i] = T[c4 + i][r];
    u16* dst = Wt + (size_t)(n0 + r) * 1024 + k0 + c4;
    *(s16x8*)dst = *(s16x8*)tmp;
    *(s16x8*)(dst + 8) = *(s16x8*)(tmp + 8);
  }
}

// ---------------------------------------------------------------------------
// Kernel 1: xW = x_flat(32768x1024) @ W(1024x4096), bf16 MFMA, out bf16.
// Output layout: XW[ugrp64][t][b][ul16*4 + gate]  (one dwordx2 per thread)
// ---------------------------------------------------------------------------
template <int WT>
__global__ __launch_bounds__(256) void xw_gemm(const float* __restrict__ X,
                                               const float* __restrict__ W,
                                               const u16* __restrict__ Wt,
                                               u16* __restrict__ XW) {
  __shared__ u16 Al[128][72];
  __shared__ u16 Bl[128][72];
  const int tid = threadIdx.x;
  const int lane = tid & 63;
  const int wv = tid >> 6;
  const int m0 = (blockIdx.x >> 5) * 128;
  const int n0 = (blockIdx.x & 31) * 128;
  f32x4 acc[4][4];
#pragma unroll
  for (int i = 0; i < 4; ++i)
#pragma unroll
    for (int j = 0; j < 4; ++j) acc[i][j] = (f32x4){0.f, 0.f, 0.f, 0.f};

  for (int kt = 0; kt < 1024; kt += 64) {
    {
      const int r = tid >> 1, hh = (tid & 1) * 32;
      const float* src = X + (size_t)(m0 + r) * 1024 + kt + hh;
      u16* dst = &Al[r][hh];
      if constexpr (WT) {
#pragma unroll
        for (int j = 0; j < 4; ++j) {
          float4 v0 = ((const float4*)src)[2 * j];
          float4 v1 = ((const float4*)src)[2 * j + 1];
          u32x4 q;
          q[0] = ((unsigned)f2bf(v0.y) << 16) | f2bf(v0.x);
          q[1] = ((unsigned)f2bf(v0.w) << 16) | f2bf(v0.z);
          q[2] = ((unsigned)f2bf(v1.y) << 16) | f2bf(v1.x);
          q[3] = ((unsigned)f2bf(v1.w) << 16) | f2bf(v1.z);
          *(u32x4*)(dst + j * 8) = q;
        }
      } else {
#pragma unroll
        for (int j = 0; j < 8; ++j) {
          float4 v = ((const float4*)src)[j];
          dst[j * 4 + 0] = f2bf(v.x); dst[j * 4 + 1] = f2bf(v.y);
          dst[j * 4 + 2] = f2bf(v.z); dst[j * 4 + 3] = f2bf(v.w);
        }
      }
    }
    if constexpr (WT) {
      const int n = tid >> 1, kh = (tid & 1) * 32;
      const u16* src = Wt + (size_t)(n0 + n) * 1024 + kt + kh;
      u16* dst = &Bl[n][kh];
#pragma unroll
      for (int j = 0; j < 4; ++j)
        *(s16x8*)(dst + j * 8) = *(const s16x8*)(src + j * 8);
    } else {
      const int kr = tid >> 2, q = (tid & 3) * 32;
      const float* src = W + (size_t)(kt + kr) * 4096 + n0 + q;
#pragma unroll
      for (int j = 0; j < 8; ++j) {
        float4 v = ((const float4*)src)[j];
        const int n = q + j * 4;
        Bl[n + 0][kr] = f2bf(v.x); Bl[n + 1][kr] = f2bf(v.y);
        Bl[n + 2][kr] = f2bf(v.z); Bl[n + 3][kr] = f2bf(v.w);
      }
    }
    __syncthreads();
    const int wm = (wv >> 1) * 64, wn = (wv & 1) * 64;
    const int row = lane & 15, kq = (lane >> 4) * 8;
#pragma unroll
    for (int ks = 0; ks < 2; ++ks) {
      s16x8 af[4], bq[4];
#pragma unroll
      for (int i = 0; i < 4; ++i) af[i] = *(const s16x8*)&Al[wm + i * 16 + row][ks * 32 + kq];
#pragma unroll
      for (int j = 0; j < 4; ++j) bq[j] = *(const s16x8*)&Bl[wn + j * 16 + row][ks * 32 + kq];
#pragma unroll
      for (int i = 0; i < 4; ++i)
#pragma unroll
        for (int j = 0; j < 4; ++j) acc[i][j] = mfma16(af[i], bq[j], acc[i][j]);
    }
    __syncthreads();
  }
  const int wm = (wv >> 1) * 64, wn = (wv & 1) * 64;
  const int col16 = lane & 15, rq = (lane >> 4) * 4;
#pragma unroll
  for (int i = 0; i < 4; ++i)
#pragma unroll
    for (int j = 0; j < 4; ++j)
#pragma unroll
      for (int q = 0; q < 4; ++q) {
        const int m = m0 + wm + i * 16 + rq + q;
        const int n = n0 + wn + j * 16 + col16;   // 0..4095 = g*1024 + u
        const int t = m & 511, b = m >> 9;
        const int g = n >> 10, uu = n & 1023;
        const int ugrp = uu >> 4, ul2 = uu & 15;
        XW[(((size_t)ugrp * 512 + t) * 64 + b) * 64 + ul2 * 4 + g] = f2bf(acc[i][j][q]);
      }
}

// ---------------------------------------------------------------------------
// Kernel 2: init h/c seed buffers from h0/c0
// ---------------------------------------------------------------------------
__global__ void init_comm(const float* __restrict__ h0, const float* __restrict__ c0,
                          u16* hini, u16* cini) {
  const int i = blockIdx.x * 256 + threadIdx.x;
  hini[i] = f2bf(h0[i]);
  cini[i] = f2bf(c0[i]);
}

// ---------------------------------------------------------------------------
// Flag barrier over the block's row-quarter domain (64 blocks, 4 independent
// domains). bid = ugrp*4 + rq. arrive: syncthreads + t0 far-atomic epoch.
// poll: thread tid polls peer (tid&63) of its domain; embedded vmcnt(0) also
// drains any loads the caller issued pre-poll; sched_barrier fences consumers.
// ---------------------------------------------------------------------------
__device__ __forceinline__ void gbar_arrive(unsigned int* flags, int bid, int tid,
                                            unsigned int ep) {
  __syncthreads();
  if (tid == 0) atomic_swap_u32(flags + bid * 16, ep);
}
__device__ __forceinline__ void gbar_poll(unsigned int* flags, int rq, int tid,
                                          unsigned int ep) {
  unsigned int* f = flags + ((((tid & 63) << 2) | rq) * 16);
  for (;;) {
    unsigned int v;
    asm volatile("global_load_dword %0, %1, off sc0 sc1\n\ts_waitcnt vmcnt(0)"
                 : "=v"(v) : "v"(f) : "memory");
    if (v >= ep) break;
    __builtin_amdgcn_s_sleep(1);
  }
  __builtin_amdgcn_sched_barrier(0);
}

// ---------------------------------------------------------------------------
// Kernel 3: persistent recurrence. 256 blocks = 64 ugrps x 4 row-quarters,
// block = 16 u-columns x 16 batch rows. R panels live in REGISTERS (one
// 16-col x 1024-k panel per wave = 128 VGPR, statically indexed); Pi/Pf/Po/
// proj (64 cols) live in LDS. All 4 waves read the same 16-row A-tiles ->
// L1 dedups the 4x intra-block amplification; L3 broadcast traffic halves
// vs the 8u x 32row layout. Protocol identical to R5/R9 (far-atomic publish,
// flag barrier, t-indexed stage slots, counted-vmcnt prefetch).
// ---------------------------------------------------------------------------
#define WLDS_B   (64 * 1032 * 2)          // 132096
#define ZOFF     WLDS_B
#define POFF     (ZOFF + 16 * 68 * 4)     // 136448
#define OOFF     (POFF + 16 * 36 * 4)     // 138752
#define SMEM_B   (OOFF + 16 * 36 * 4)     // 141056
#define STEP_E   65536                     // elements per stage slot (64*1024)

template <int STAGED>
__global__ __launch_bounds__(256, 1) void lstm_loop(
    const float* __restrict__ rec, const float* __restrict__ peep,
    const float* __restrict__ projw, const float* __restrict__ bias,
    const float* __restrict__ x, const u16* __restrict__ xw,
    float* __restrict__ out,
    u16* hini, u16* cini, u16* cb0, u16* cb1, u16* thsg,
    u16* hst, u16* cst, u16* thst,
    unsigned int* flags, const float* __restrict__ c0) {
  extern __shared__ char smem[];
  u16 (*wlds)[1032] = (u16(*)[1032])smem;
  float (*zlds)[68] = (float(*)[68])(smem + ZOFF);
  float (*plds)[36] = (float(*)[36])(smem + POFF);
  float (*olds)[36] = (float(*)[36])(smem + OOFF);

  const int tid = threadIdx.x;
  const int lane = tid & 63;
  const int wv = tid >> 6;
  const int bid = blockIdx.x;
  const int ugrp = bid >> 2;
  const int rq = bid & 3;
  const int row0 = rq * 16;
  const int u0 = ugrp * 16;
  const int fcol = lane & 15;
  const int kofs = (lane >> 4) * 8;

  // ---- pass A: stage R (64 cols, gate-major: col c -> gate c>>4, u0+(c&15)) ----
  for (int g = 0; g < 8; ++g) {
    const int c = g * 8 + (tid & 3) * 2;
    const int scol = (c >> 4) * 1024 + u0 + (c & 15);
#pragma unroll 4
    for (int p = 0; p < 16; ++p) {
      const int k = p * 64 + (tid >> 2);
      float2 v = *(const float2*)(rec + (size_t)k * 4096 + scol);
      wlds[c][k] = f2bf(v.x);
      wlds[c + 1][k] = f2bf(v.y);
    }
  }
  __syncthreads();
  // extract this wave's R panel into registers (statically indexed)
  s16x8 breg[32];
#pragma unroll
  for (int kt = 0; kt < 32; ++kt)
    breg[kt] = *(const s16x8*)&wlds[wv * 16 + fcol][kt * 32 + kofs];
  __syncthreads();
  // ---- pass B: Pi(0-15) Pf(16-31) Po(32-47) proj(48-63) ----
  for (int g = 0; g < 8; ++g) {
    const int c = g * 8 + (tid & 3) * 2;
    const float* sp; int stride, scol;
    if (c < 48) { sp = peep;  stride = 3072; scol = (c >> 4) * 1024 + u0 + (c & 15); }
    else        { sp = projw; stride = 1024; scol = u0 + (c & 15); }
#pragma unroll 4
    for (int p = 0; p < 16; ++p) {
      const int k = p * 64 + (tid >> 2);
      float2 v = *(const float2*)(sp + (size_t)k * stride + scol);
      wlds[c][k] = f2bf(v.x);
      wlds[c + 1][k] = f2bf(v.y);
    }
  }

  const int r = tid >> 4;        // 0..15 local row
  const int ul = tid & 15;       // 0..15 local u
  const int brow = row0 + r;
  const int u = u0 + ul;
  const float b_i = bias[u], b_f = bias[1024 + u], b_c = bias[2048 + u], b_o = bias[3072 + u];
  float cstv = c0[brow * 1024 + u];

  u32x2 xwp;       // prefetched xw gates for step t
  float xp;        // prefetched x residual for step t
  {
    const u16* xr0 = xw + (((size_t)ugrp * 512 + 0) * 64 + brow) * 64 + ul * 4;
    asm volatile("global_load_dwordx2 %0, %1, off" : "=v"(xwp) : "v"(xr0));
    const float* xs0 = x + (size_t)brow * (512 * 1024) + u;
    asm volatile("global_load_dword %0, %1, off" : "=v"(xp) : "v"(xs0));
  }
  __syncthreads();   // pass-B weights visible

  for (int t = 0; t < NT; ++t) {
    const size_t xo = (size_t)brow * (512 * 1024) + (size_t)t * 1024 + u;
    float zo_reg, xres, hv;

    // per-step buffers
    const u16 *hsrc, *cpsrc, *csrc, *thsrc; u16 *cpub, *thpub, *hpub;
    if constexpr (STAGED) {
      hsrc  = t ? (hst + (size_t)(t - 1) * STEP_E) : hini;
      cpsrc = t ? (cst + (size_t)(t - 1) * STEP_E) : cini;
      cpub  = cst + (size_t)t * STEP_E;   csrc = cpub;
      thpub = thst + (size_t)t * STEP_E;  thsrc = thpub;
      hpub  = hst + (size_t)t * STEP_E;
    } else {
      hsrc = hini; hpub = hini;
      cpub = (t & 1) ? cb1 : cb0; csrc = cpub;
      cpsrc = (t == 0) ? cini : ((t & 1) ? cb0 : cb1);
      thpub = thsg; thsrc = thsg;
    }

    // ===== phase 1: z = h@R (reg panels, all waves); waves 0-1 + peephole =====
    s16x8 av[32];
    if (wv < 2) {
      s16x8 cv[32];
      {  // c_prev loads issued BEFORE the poll: drained by the poll's vmcnt(0)
        const u16* ap = cpsrc + (size_t)(row0 + fcol) * 1024 + kofs;
#pragma unroll
        for (int kt = 0; kt < 32; ++kt) ldx4<STAGED>(cv[kt], ap + kt * 32);
      }
      gbar_poll(flags, rq, tid, 2 * (unsigned)t);       // h(t-1) published
      // peephole first (cv ready), then h loads: caps register pressure
      f32x4 accP = {0.f, 0.f, 0.f, 0.f};
      const u16* bp = &wlds[wv * 16 + fcol][kofs];      // wave0 Pi, wave1 Pf
#pragma unroll
      for (int kt = 0; kt < 32; ++kt)
        accP = mfma16(cv[kt], *(const s16x8*)(bp + kt * 32), accP);
      {
        const u16* ap = hsrc + (size_t)(row0 + fcol) * 1024 + kofs;
#pragma unroll
        for (int kt = 0; kt < 32; ++kt) ldx4<STAGED>(av[kt], ap + kt * 32);
      }
      WAIT_VM0();
      f32x4 accZ = {0.f, 0.f, 0.f, 0.f};
#pragma unroll
      for (int kt = 0; kt < 32; ++kt) accZ = mfma16(av[kt], breg[kt], accZ);
      const int srow = (lane >> 4) * 4;
#pragma unroll
      for (int q = 0; q < 4; ++q) {
        zlds[srow + q][wv * 16 + fcol] = accZ[q];
        plds[srow + q][wv * 16 + fcol] = accP[q];
      }
    } else {
      gbar_poll(flags, rq, tid, 2 * (unsigned)t);
      {
        const u16* ap = hsrc + (size_t)(row0 + fcol) * 1024 + kofs;
#pragma unroll
        for (int kt = 0; kt < 32; ++kt) ldx4<STAGED>(av[kt], ap + kt * 32);
      }
      WAIT_VM0();
      f32x4 accZ = {0.f, 0.f, 0.f, 0.f};
#pragma unroll
      for (int kt = 0; kt < 32; ++kt) accZ = mfma16(av[kt], breg[kt], accZ);
      const int srow = (lane >> 4) * 4;
#pragma unroll
      for (int q = 0; q < 4; ++q) zlds[srow + q][wv * 16 + fcol] = accZ[q];
    }
    __syncthreads();
    {
      // gate math (xwp/xp drained by the poll)
      const float xw_i = bf2f((u16)(xwp[0] & 0xffffu));
      const float xw_f = bf2f((u16)(xwp[0] >> 16));
      const float xw_c = bf2f((u16)(xwp[1] & 0xffffu));
      const float xw_o = bf2f((u16)(xwp[1] >> 16));
      xres = xp;
      const float zi = zlds[r][ul]      + xw_i + b_i + plds[r][ul];
      const float zf = zlds[r][16 + ul] + xw_f + b_f + plds[r][16 + ul];
      const float zc = zlds[r][32 + ul] + xw_c + b_c;
      zo_reg         = zlds[r][48 + ul] + xw_o + b_o;
      const float ig = hsig(zi), fg = hsig(zf);
      cstv = fg * cstv + ig * ftanh(zc);
      const float th = ftanh(cstv);
      const unsigned int cb = f2bf(cstv), tb = f2bf(th);
      const unsigned int cp = ((unsigned)__shfl_xor((int)cb, 1) << 16) | cb;
      const unsigned int tp = ((unsigned)__shfl_xor((int)tb, 1) << 16) | tb;
      const unsigned int cp2 = (unsigned)__shfl_xor((int)cp, 2);
      const unsigned int tp2 = (unsigned)__shfl_xor((int)tp, 2);
      if ((ul & 3) == 0) {
        u32x2 cq; cq[0] = cp; cq[1] = cp2;
        u32x2 tq; tq[0] = tp; tq[1] = tp2;
        atomic_swap_u64((unsigned int*)(cpub + brow * 1024 + u), cq);
        atomic_swap_u64((unsigned int*)(thpub + brow * 1024 + u), tq);
      }
    }
    WAIT_VM0();
    gbar_arrive(flags, bid, tid, 2 * t + 1);            // c_new / th published

    // ===== phase 2: wave2 Po (A=c_new), wave3 proj (A=th) =====
    if (!STAGED || wv >= 2) gbar_poll(flags, rq, tid, 2 * t + 1);
    if (wv >= 2) {
      const u16* ap = ((wv == 2) ? csrc : thsrc)
                      + (size_t)(row0 + fcol) * 1024 + kofs;
#pragma unroll
      for (int kt = 0; kt < 32; ++kt) ldx4<STAGED>(av[kt], ap + kt * 32);
      WAIT_VM0();
      f32x4 acc = {0.f, 0.f, 0.f, 0.f};
      const u16* bp = &wlds[wv * 16 + fcol][kofs];      // wave2 Po(32-47), wave3 proj(48-63)
#pragma unroll
      for (int kt = 0; kt < 32; ++kt)
        acc = mfma16(av[kt], *(const s16x8*)(bp + kt * 32), acc);
      const int srow = (lane >> 4) * 4;
#pragma unroll
      for (int q = 0; q < 4; ++q) olds[srow + q][(wv - 2) * 16 + fcol] = acc[q];
    }
    __syncthreads();
    {
      const float og = hsig(zo_reg + olds[r][ul]);
      const float pv = olds[r][16 + ul] + xres;
      hv = og * pv;
      const unsigned int hb = f2bf(hv);
      const unsigned int hp = ((unsigned)__shfl_xor((int)hb, 1) << 16) | hb;
      const unsigned int hp2 = (unsigned)__shfl_xor((int)hp, 2);
      if ((ul & 3) == 0) {
        u32x2 hq; hq[0] = hp; hq[1] = hp2;
        atomic_swap_u64((unsigned int*)(hpub + brow * 1024 + u), hq);
      }
      // next-step prefetch + out store stay in flight across barrier B
      const int tn = (t + 1 < NT) ? (t + 1) : t;
      const u16* xrn = xw + (((size_t)ugrp * 512 + tn) * 64 + brow) * 64 + ul * 4;
      asm volatile("global_load_dwordx2 %0, %1, off" : "=v"(xwp) : "v"(xrn));
      const float* xsn = x + (size_t)brow * (512 * 1024) + (size_t)tn * 1024 + u;
      asm volatile("global_load_dword %0, %1, off" : "=v"(xp) : "v"(xsn));
      asm volatile("global_store_dword %0, %1, off" :: "v"(out + xo), "v"(hv) : "memory");
      WAIT_VM(3);          // h atomic acked; prefetch/out still flying
    }
    gbar_arrive(flags, bid, tid, 2 * t + 2);            // h published
  }
}

// ---------------------------------------------------------------------------
// Host launcher
// ---------------------------------------------------------------------------
extern "C" void kernel_launch(void* const* d_in, const int* in_sizes, int n_in,
                              void* d_out, int out_size, void* d_ws, size_t ws_size,
                              hipStream_t stream) {
  const float* x    = (const float*)d_in[0];
  const float* h0   = (const float*)d_in[1];
  const float* c0   = (const float*)d_in[2];
  const float* W    = (const float*)d_in[3];
  const float* R    = (const float*)d_in[4];
  const float* P    = (const float*)d_in[5];
  const float* PRJ  = (const float*)d_in[6];
  const float* bias = (const float*)d_in[7];
  float* out = (float*)d_out;
  char* ws = (char*)d_ws;

  const size_t XW_BYTES = (size_t)32768 * 4096 * 2;   // 268435456
  size_t off = XW_BYTES;
  u16* xw   = (u16*)ws;
  u16* hini = (u16*)(ws + off); off += 131072;
  u16* cini = (u16*)(ws + off); off += 131072;
  u16* cb0  = (u16*)(ws + off); off += 131072;
  u16* cb1  = (u16*)(ws + off); off += 131072;
  u16* thsg = (u16*)(ws + off); off += 131072;
  unsigned int* flags = (unsigned int*)(ws + off); off += 16384;
  const size_t base_need = off;
  u16* hst = (u16*)(ws + off);  off += (size_t)NT * 131072;
  u16* cst = (u16*)(ws + off);  off += (size_t)NT * 131072;
  u16* thst = (u16*)(ws + off); off += (size_t)NT * 131072;
  const size_t staged_need = off;
  u16* Wt = (u16*)(ws + off); off += (size_t)4096 * 1024 * 2;   // 8 MB
  const size_t wt_need = off;
  if (ws_size < base_need) return;
  const int staged = (ws_size >= staged_need) ? 1 : 0;
  const int wt = (ws_size >= wt_need) ? 1 : 0;

  (void)hipFuncSetAttribute(reinterpret_cast<const void*>(&lstm_loop<1>),
                            hipFuncAttributeMaxDynamicSharedMemorySize, 160 * 1024);
  (void)hipFuncSetAttribute(reinterpret_cast<const void*>(&lstm_loop<0>),
                            hipFuncAttributeMaxDynamicSharedMemorySize, 160 * 1024);

  hipMemsetAsync(flags, 0, 16384, stream);
  hipLaunchKernelGGL(init_comm, dim3(256), dim3(256), 0, stream, h0, c0, hini, cini);
  if (wt) {
    hipLaunchKernelGGL(wt_cvt, dim3(1024), dim3(256), 0, stream, W, Wt);
    hipLaunchKernelGGL((xw_gemm<1>), dim3(8192), dim3(256), 0, stream, x, W, Wt, xw);
  } else {
    hipLaunchKernelGGL((xw_gemm<0>), dim3(8192), dim3(256), 0, stream, x, W, Wt, xw);
  }

  void* args[17];
  args[0] = (void*)&R;     args[1] = (void*)&P;     args[2] = (void*)&PRJ;
  args[3] = (void*)&bias;  args[4] = (void*)&x;     args[5] = (void*)&xw;
  args[6] = (void*)&out;   args[7] = (void*)&hini;  args[8] = (void*)&cini;
  args[9] = (void*)&cb0;   args[10] = (void*)&cb1;  args[11] = (void*)&thsg;
  args[12] = (void*)&hst;  args[13] = (void*)&cst;  args[14] = (void*)&thst;
  args[15] = (void*)&flags; args[16] = (void*)&c0;

  const void* fn = staged ? (const void*)&lstm_loop<1> : (const void*)&lstm_loop<0>;
  hipError_t e = hipLaunchCooperativeKernel(fn, dim3(256), dim3(256),
                                            args, (unsigned int)SMEM_B, stream);
  if (e != hipSuccess) {
    if (staged)
      hipLaunchKernelGGL((lstm_loop<1>), dim3(256), dim3(256), SMEM_B, stream,
                         R, P, PRJ, bias, x, xw, out, hini, cini, cb0, cb1, thsg,
                         hst, cst, thst, flags, c0);
    else
      hipLaunchKernelGGL((lstm_loop<0>), dim3(256), dim3(256), SMEM_B, stream,
                         R, P, PRJ, bias, x, xw, out, hini, cini, cb0, cb1, thsg,
                         hst, cst, thst, flags, c0);
  }
}